// Round 1
// baseline (158.365 us; speedup 1.0000x reference)
//
#include <hip/hip_runtime.h>

// Problem constants (B=8, N=M=8192, D=3, fp32).
constexpr int B     = 8;
constexpr int NPTS  = 8192;          // points per batch, both inputs
constexpr int TOTAL = B * NPTS;      // 65536 points per input
constexpr int TN    = 2048;          // A-points per block (256 thr * P)
constexpr int TM    = 1024;          // candidates staged in LDS per block
constexpr int P     = 8;             // points per thread

// Pack [B*N,3] fp32 -> float4(x,y,z, x^2+y^2+z^2) for both inputs.
__global__ __launch_bounds__(256) void pack_kernel(
    const float* __restrict__ in1, const float* __restrict__ in2,
    float4* __restrict__ p1, float4* __restrict__ p2)
{
    int i = blockIdx.x * 256 + threadIdx.x;   // grid exactly covers TOTAL
    float a = in1[3*i], b = in1[3*i+1], c = in1[3*i+2];
    p1[i] = make_float4(a, b, c, fmaf(a, a, fmaf(b, b, c*c)));
    a = in2[3*i]; b = in2[3*i+1]; c = in2[3*i+2];
    p2[i] = make_float4(a, b, c, fmaf(a, a, fmaf(b, b, c*c)));
}

// For each A-point: min over a TM-chunk of B-candidates of
//   d = sq1 + sq2 - 2<x,y>, folded as  sq1 + min_m( sq2[m] - 2 t ).
// Clamp max(d,0) commutes with min (monotone), applied at the end.
// Partial mins across m-chunks merged via atomicMin on uint
// (valid: all values >= 0, bit pattern order == float order).
__global__ __launch_bounds__(256) void chamfer_min(
    const float4* __restrict__ p1, const float4* __restrict__ p2,
    unsigned int* __restrict__ dist)
{
    const int z   = blockIdx.z;
    const int dir = z >> 3;          // 0: input1->input2, 1: input2->input1
    const int b   = z & 7;

    const float4* A  = (dir ? p2 : p1) + (size_t)b * NPTS;
    const float4* Bc = (dir ? p1 : p2) + (size_t)b * NPTS;
    unsigned int* out = dist + (size_t)dir * TOTAL + (size_t)b * NPTS;

    __shared__ float4 lds[TM];
    const int mbase = blockIdx.y * TM;
    for (int i = threadIdx.x; i < TM; i += 256)
        lds[i] = Bc[mbase + i];
    __syncthreads();

    const int nbase = blockIdx.x * TN + threadIdx.x;
    float x0[P], x1[P], x2[P], sq[P], mn[P];
#pragma unroll
    for (int p = 0; p < P; ++p) {
        float4 a = A[nbase + p * 256];
        x0[p] = a.x; x1[p] = a.y; x2[p] = a.z; sq[p] = a.w;
        mn[p] = 1e30f;
    }

#pragma unroll 4
    for (int j = 0; j < TM; ++j) {
        float4 c = lds[j];           // wave-uniform address: LDS broadcast
#pragma unroll
        for (int p = 0; p < P; ++p) {
            float t = fmaf(x0[p], c.x, fmaf(x1[p], c.y, x2[p] * c.z));
            float e = fmaf(-2.0f, t, c.w);     // sq2[m] - 2<x,y>
            mn[p] = fminf(mn[p], e);
        }
    }

#pragma unroll
    for (int p = 0; p < P; ++p) {
        float d = fmaxf(mn[p] + sq[p], 0.0f);
        atomicMin(&out[nbase + p * 256], __float_as_uint(d));
    }
}

// loss = mean(dist1) + mean(dist2) = (sum of ALL 2*TOTAL mins) / TOTAL
__global__ __launch_bounds__(256) void reduce_kernel(
    const unsigned int* __restrict__ dist, float* __restrict__ out)
{
    int base = blockIdx.x * 1024 + threadIdx.x;
    float v = 0.0f;
#pragma unroll
    for (int k = 0; k < 4; ++k)
        v += __uint_as_float(dist[base + k * 256]);
#pragma unroll
    for (int off = 32; off; off >>= 1)
        v += __shfl_down(v, off, 64);
    __shared__ float wsum[4];
    int lane = threadIdx.x & 63, w = threadIdx.x >> 6;
    if (lane == 0) wsum[w] = v;
    __syncthreads();
    if (threadIdx.x == 0)
        atomicAdd(out, (wsum[0] + wsum[1] + wsum[2] + wsum[3]) *
                           (1.0f / (float)TOTAL));
}

extern "C" void kernel_launch(void* const* d_in, const int* in_sizes, int n_in,
                              void* d_out, int out_size, void* d_ws, size_t ws_size,
                              hipStream_t stream)
{
    const float* in1 = (const float*)d_in[0];
    const float* in2 = (const float*)d_in[1];
    float* out = (float*)d_out;

    char* ws = (char*)d_ws;
    float4* p1 = (float4*)ws;                                  // 1 MiB
    float4* p2 = (float4*)(ws + (size_t)TOTAL * 16);           // 1 MiB
    unsigned int* dist = (unsigned int*)(ws + (size_t)2 * TOTAL * 16); // 512 KiB

    // Init mins to 0xFFFFFFFF (uint max, beats every non-negative float);
    // zero the output accumulator (harness poisons both each replay).
    hipMemsetAsync(dist, 0xFF, (size_t)2 * TOTAL * 4, stream);
    hipMemsetAsync(out, 0, sizeof(float), stream);

    pack_kernel<<<TOTAL / 256, 256, 0, stream>>>(in1, in2, p1, p2);
    chamfer_min<<<dim3(NPTS / TN, NPTS / TM, 2 * B), 256, 0, stream>>>(p1, p2, dist);
    reduce_kernel<<<(2 * TOTAL) / 1024, 256, 0, stream>>>(dist, out);
}

// Round 2
// 155.207 us; speedup vs baseline: 1.0203x; 1.0203x over previous
//
#include <hip/hip_runtime.h>

// Chamfer distance, B=8, N=M=8192, D=3, fp32.
// Strategy: candidate points pre-scaled to (-2x,-2y,-2z,||c||^2) so
// dist-term = fma(x,Cx, fma(y,Cy, fma(z,Cz, Cw))) — 3 FMA + 1 min per pair.
// Points paired into float2 ext-vectors -> v_pk_fma_f32 (full-rate packed
// fp32 on gfx950) => ~2.5 VALU issues/pair, floor ~34 us.

typedef float f2 __attribute__((ext_vector_type(2)));

constexpr int B     = 8;
constexpr int NPTS  = 8192;
constexpr int TOTAL = B * NPTS;      // 65536
constexpr int TN    = 2048;          // A-points per block
constexpr int TM    = 512;           // candidates staged in LDS per block
constexpr int NCH   = NPTS / TM;     // 16 candidate chunks
constexpr int P     = 8;             // points per thread
constexpr int Q     = P / 2;         // float2 pairs per thread

// Pack [B*N,3] -> raw float4(x,y,z,sq) for the A role and
// scaled float4(-2x,-2y,-2z,sq) for the candidate role, both inputs.
__global__ __launch_bounds__(256) void pack_kernel(
    const float* __restrict__ in1, const float* __restrict__ in2,
    float4* __restrict__ raw1, float4* __restrict__ raw2,
    float4* __restrict__ sc1,  float4* __restrict__ sc2)
{
    int i = blockIdx.x * 256 + threadIdx.x;
    float a = in1[3*i], b = in1[3*i+1], c = in1[3*i+2];
    float s = fmaf(a, a, fmaf(b, b, c*c));
    raw1[i] = make_float4(a, b, c, s);
    sc1[i]  = make_float4(-2.f*a, -2.f*b, -2.f*c, s);
    a = in2[3*i]; b = in2[3*i+1]; c = in2[3*i+2];
    s = fmaf(a, a, fmaf(b, b, c*c));
    raw2[i] = make_float4(a, b, c, s);
    sc2[i]  = make_float4(-2.f*a, -2.f*b, -2.f*c, s);
}

// grid (NPTS/TN, NCH, 16). z = dir*8+b. Each block mins its TM-chunk of
// candidates into a per-chunk output plane (no atomics, no init needed):
// dist[((z*NCH)+chunk)*NPTS + n] = clamp(min_chunk + sq, 0).
// Clamp commutes with the cross-chunk min (monotone).
__global__ __launch_bounds__(256) void chamfer_min(
    const float4* __restrict__ raw1, const float4* __restrict__ raw2,
    const float4* __restrict__ sc1,  const float4* __restrict__ sc2,
    float* __restrict__ dist)
{
    const int z   = blockIdx.z;
    const int dir = z >> 3;
    const int b   = z & 7;

    const float4* A = (dir ? raw2 : raw1) + (size_t)b * NPTS;
    const float4* C = (dir ? sc1  : sc2)  + (size_t)b * NPTS;
    float* out = dist + ((size_t)z * NCH + blockIdx.y) * NPTS;

    __shared__ float4 lds[TM];
    const int mbase = blockIdx.y * TM;
    for (int i = threadIdx.x; i < TM; i += 256)
        lds[i] = C[mbase + i];
    __syncthreads();

    const int nbase = blockIdx.x * TN + threadIdx.x;
    f2 X[Q], Y[Q], Zc[Q], SQ[Q], MN[Q];
#pragma unroll
    for (int q = 0; q < Q; ++q) {
        float4 a0 = A[nbase + (2*q)   * 256];
        float4 a1 = A[nbase + (2*q+1) * 256];
        X[q]  = f2{a0.x, a1.x};
        Y[q]  = f2{a0.y, a1.y};
        Zc[q] = f2{a0.z, a1.z};
        SQ[q] = f2{a0.w, a1.w};
        MN[q] = f2{1e30f, 1e30f};
    }

#pragma unroll 4
    for (int j = 0; j < TM; ++j) {
        float4 c = lds[j];               // wave-uniform addr: LDS broadcast
        f2 cx = f2{c.x, c.x}, cy = f2{c.y, c.y};
        f2 cz = f2{c.z, c.z}, cw = f2{c.w, c.w};
#pragma unroll
        for (int q = 0; q < Q; ++q) {
            f2 e = __builtin_elementwise_fma(X[q], cx,
                   __builtin_elementwise_fma(Y[q], cy,
                   __builtin_elementwise_fma(Zc[q], cz, cw)));
            MN[q] = __builtin_elementwise_min(MN[q], e);
        }
    }

#pragma unroll
    for (int q = 0; q < Q; ++q) {
        f2 d = MN[q] + SQ[q];
        out[nbase + (2*q)   * 256] = fmaxf(d.x, 0.0f);
        out[nbase + (2*q+1) * 256] = fmaxf(d.y, 0.0f);
    }
}

// One thread per (z,n) point: min over the NCH chunk planes, then
// block-sum -> atomicAdd(out, sum/TOTAL). loss = (sum of all mins)/TOTAL
// since both directions have TOTAL points.
__global__ __launch_bounds__(256) void reduce_kernel(
    const float* __restrict__ dist, float* __restrict__ out)
{
    int g = blockIdx.x * 256 + threadIdx.x;     // [0, 2*TOTAL)
    int z = g >> 13;                            // 16 planes-of-origin
    int n = g & (NPTS - 1);
    const float* base = dist + (size_t)z * NCH * NPTS + n;
    float v = base[0];
#pragma unroll
    for (int cy = 1; cy < NCH; ++cy)
        v = fminf(v, base[(size_t)cy * NPTS]);

#pragma unroll
    for (int off = 32; off; off >>= 1)
        v += __shfl_down(v, off, 64);
    __shared__ float wsum[4];
    int lane = threadIdx.x & 63, w = threadIdx.x >> 6;
    if (lane == 0) wsum[w] = v;
    __syncthreads();
    if (threadIdx.x == 0)
        atomicAdd(out, (wsum[0] + wsum[1] + wsum[2] + wsum[3]) *
                           (1.0f / (float)TOTAL));
}

extern "C" void kernel_launch(void* const* d_in, const int* in_sizes, int n_in,
                              void* d_out, int out_size, void* d_ws, size_t ws_size,
                              hipStream_t stream)
{
    const float* in1 = (const float*)d_in[0];
    const float* in2 = (const float*)d_in[1];
    float* out = (float*)d_out;

    char* ws = (char*)d_ws;
    const size_t PB = (size_t)TOTAL * 16;       // 1 MiB per packed buffer
    float4* raw1 = (float4*)(ws);
    float4* raw2 = (float4*)(ws + PB);
    float4* sc1  = (float4*)(ws + 2 * PB);
    float4* sc2  = (float4*)(ws + 3 * PB);
    float*  dist = (float*)(ws + 4 * PB);       // 16 z * 16 ch * 8192 * 4B = 8 MiB

    hipMemsetAsync(out, 0, sizeof(float), stream);   // atomicAdd accumulator

    pack_kernel<<<TOTAL / 256, 256, 0, stream>>>(in1, in2, raw1, raw2, sc1, sc2);
    chamfer_min<<<dim3(NPTS / TN, NCH, 2 * B), 256, 0, stream>>>(
        raw1, raw2, sc1, sc2, dist);
    reduce_kernel<<<(2 * TOTAL) / 256, 256, 0, stream>>>(dist, out);
}

// Round 3
// 140.678 us; speedup vs baseline: 1.1257x; 1.1033x over previous
//
#include <hip/hip_runtime.h>

// Chamfer distance, B=8, N=M=8192, D=3, fp32.
// d(n,m) = ||a||^2 + min_m( fma(ax,-2cx, fma(ay,-2cy, fma(az,-2cz, ||c||^2))) )
// Candidates staged in LDS pair-SoA so v_pk_fma_f32 (forced via inline asm,
// full-rate packed fp32) processes 2 candidates per chain; the two halves
// merge into the running min with one v_min3_f32.
// => 2.0 VALU issues/pair, floor ~27 us busy across 1024 SIMDs.

typedef float f2 __attribute__((ext_vector_type(2)));

constexpr int B     = 8;
constexpr int NPTS  = 8192;
constexpr int TOTAL = B * NPTS;      // 65536
constexpr int TN    = 2048;          // A-points per block (256 thr * P)
constexpr int TM    = 512;           // candidates per block chunk
constexpr int NCH   = NPTS / TM;     // 16 candidate chunks
constexpr int P     = 8;             // A-points per thread

// grid (NPTS/TN=4, NCH=16, 16).  z = dir*8 + b.
// Writes per-chunk partial-min planes: dist[(z*NCH+chunk)*NPTS + n].
// max(d,0) clamp commutes with the cross-chunk min (monotone).
__global__ __launch_bounds__(256, 4) void chamfer_min(
    const float* __restrict__ in1, const float* __restrict__ in2,
    float* __restrict__ dist)
{
    const int z   = blockIdx.z;
    const int dir = z >> 3;
    const int b   = z & 7;

    const float* Araw = (dir ? in2 : in1) + (size_t)b * NPTS * 3;
    const float* Craw = (dir ? in1 : in2) + (size_t)b * NPTS * 3;
    float* out = dist + ((size_t)z * NCH + blockIdx.y) * NPTS;

    // Stage + pack candidate chunk into LDS, pair-SoA:
    // lds[2k]   = (-2x0, -2x1, -2y0, -2y1)
    // lds[2k+1] = (-2z0, -2z1, sq0,  sq1)
    __shared__ float4 lds[TM];
    {
        const int k = threadIdx.x;                 // pair index, 256 pairs
        const float* c = Craw + (size_t)(blockIdx.y * TM + 2 * k) * 3;
        float x0 = c[0], y0 = c[1], z0 = c[2];
        float x1 = c[3], y1 = c[4], z1 = c[5];
        float s0 = fmaf(x0, x0, fmaf(y0, y0, z0 * z0));
        float s1 = fmaf(x1, x1, fmaf(y1, y1, z1 * z1));
        lds[2 * k]     = make_float4(-2.f * x0, -2.f * x1, -2.f * y0, -2.f * y1);
        lds[2 * k + 1] = make_float4(-2.f * z0, -2.f * z1, s0, s1);
    }

    // A-points: persistent splat registers {x,x},{y,y},{z,z} + sq, built once.
    const int nbase = blockIdx.x * TN + threadIdx.x;
    f2 X[P], Y[P], Z[P];
    float SQ[P], MN[P];
#pragma unroll
    for (int p = 0; p < P; ++p) {
        const float* a = Araw + (size_t)(nbase + p * 256) * 3;
        float ax = a[0], ay = a[1], az = a[2];
        X[p] = f2{ax, ax};
        Y[p] = f2{ay, ay};
        Z[p] = f2{az, az};
        SQ[p] = fmaf(ax, ax, fmaf(ay, ay, az * az));
        MN[p] = 1e30f;
    }
    __syncthreads();

#pragma unroll 2
    for (int k = 0; k < TM / 2; ++k) {
        float4 q0 = lds[2 * k];        // ds_read_b128, wave-uniform broadcast
        float4 q1 = lds[2 * k + 1];
        f2 cx = f2{q0.x, q0.y}, cy = f2{q0.z, q0.w};
        f2 cz = f2{q1.x, q1.y}, cw = f2{q1.z, q1.w};
#pragma unroll
        for (int p = 0; p < P; ++p) {
            f2 e;
            asm("v_pk_fma_f32 %0, %1, %2, %3"
                : "=v"(e) : "v"(Z[p]), "v"(cz), "v"(cw));
            asm("v_pk_fma_f32 %0, %1, %2, %3"
                : "=v"(e) : "v"(Y[p]), "v"(cy), "v"(e));
            asm("v_pk_fma_f32 %0, %1, %2, %3"
                : "=v"(e) : "v"(X[p]), "v"(cx), "v"(e));
            asm("v_min3_f32 %0, %1, %2, %3"
                : "=v"(MN[p]) : "v"(MN[p]), "v"(e.x), "v"(e.y));
        }
    }

#pragma unroll
    for (int p = 0; p < P; ++p)
        out[nbase + p * 256] = fmaxf(MN[p] + SQ[p], 0.0f);
}

// One thread per (z,n): min across the NCH chunk planes, block-sum,
// atomicAdd(out, sum/TOTAL). loss = (sum of all 2*TOTAL mins)/TOTAL.
__global__ __launch_bounds__(256) void reduce_kernel(
    const float* __restrict__ dist, float* __restrict__ out)
{
    int g = blockIdx.x * 256 + threadIdx.x;     // [0, 2*TOTAL)
    int z = g >> 13;
    int n = g & (NPTS - 1);
    const float* base = dist + (size_t)z * NCH * NPTS + n;
    float v = base[0];
#pragma unroll
    for (int cy = 1; cy < NCH; ++cy)
        v = fminf(v, base[(size_t)cy * NPTS]);

#pragma unroll
    for (int off = 32; off; off >>= 1)
        v += __shfl_down(v, off, 64);
    __shared__ float wsum[4];
    int lane = threadIdx.x & 63, w = threadIdx.x >> 6;
    if (lane == 0) wsum[w] = v;
    __syncthreads();
    if (threadIdx.x == 0)
        atomicAdd(out, (wsum[0] + wsum[1] + wsum[2] + wsum[3]) *
                           (1.0f / (float)TOTAL));
}

extern "C" void kernel_launch(void* const* d_in, const int* in_sizes, int n_in,
                              void* d_out, int out_size, void* d_ws, size_t ws_size,
                              hipStream_t stream)
{
    const float* in1 = (const float*)d_in[0];
    const float* in2 = (const float*)d_in[1];
    float* out = (float*)d_out;

    float* dist = (float*)d_ws;   // 16 z * 16 chunks * 8192 * 4B = 8 MiB

    hipMemsetAsync(out, 0, sizeof(float), stream);   // atomicAdd accumulator

    chamfer_min<<<dim3(NPTS / TN, NCH, 2 * B), 256, 0, stream>>>(in1, in2, dist);
    reduce_kernel<<<(2 * TOTAL) / 256, 256, 0, stream>>>(dist, out);
}